// Round 8
// baseline (330.953 us; speedup 1.0000x reference)
//
#include <hip/hip_runtime.h>
#include <hip/hip_bf16.h>

#define B_   4
#define C_   1024
#define CI_  512
#define NSP_ 2048   // T*H*W
#define EPS_ 1e-5f

typedef _Float16 f16x8 __attribute__((ext_vector_type(8)));
typedef float f32x4  __attribute__((ext_vector_type(4)));
typedef unsigned short ushort_t;

static __device__ inline ushort_t f2h(float v) {
    _Float16 h = (_Float16)v;
    ushort_t u;
    __builtin_memcpy(&u, &h, 2);
    return u;
}
static __device__ inline float h2f(ushort_t u) {
    _Float16 h;
    __builtin_memcpy(&h, &u, 2);
    return (float)h;
}

// ---------------- TN fp16 MFMA GEMM, 128x128 tile, BK=32 ----------------
// C[M][N] = sum_k A[i][k] * B[j][k]  (A: MxK row-major lda; B: NxK row-major ldb)
// KSPLIT: blockIdx.z = bz*KSPLIT + ks; each ks computes K/KSPLIT slice, output
//         offset ks*sK (fp32 partials when KSPLIT>1).
// STATS: per-output-row sum/sumsq accumulated to global via atomics (BN fusion).
template<bool OUT_F16, int KSPLIT, bool STATS>
__global__ __launch_bounds__(256, 2)
void gemm_tn(const ushort_t* __restrict__ A, const ushort_t* __restrict__ Bm,
             void* __restrict__ Cout,
             const float* __restrict__ biasM, const float* __restrict__ biasN,
             int N, int K, int lda, int ldb, int ldc,
             long sA, long sB, long sC, long sK,
             float* __restrict__ sums, float* __restrict__ sumsq)
{
    __shared__ ushort_t smA[128 * 32];
    __shared__ ushort_t smB[128 * 32];
    const int bz = blockIdx.z / KSPLIT;
    const int ks = blockIdx.z % KSPLIT;
    const int Ksub = K / KSPLIT;
    const ushort_t* Ag = A + bz * sA + (long)ks * Ksub;
    const ushort_t* Bg = Bm + bz * sB + (long)ks * Ksub;
    const int m0 = blockIdx.y * 128;
    const int n0 = blockIdx.x * 128;
    const int tid  = threadIdx.x;
    const int wave = tid >> 6;
    const int lane = tid & 63;
    const int wm = wave >> 1, wn = wave & 1;
    const int fr = lane & 15;      // fragment row/col within 16
    const int kg = lane >> 4;      // k-group 0..3 (8 k each)

    int offA[2], offB[2];
    #pragma unroll
    for (int t = 0; t < 2; ++t) {
        const int s   = (wave * 2 + t) * 64 + lane;  // 16B slot index in tile
        const int row = s >> 2;
        const int kc  = s & 3;
        offA[t] = (m0 + row) * lda + kc * 8;
        offB[t] = (n0 + row) * ldb + kc * 8;
    }
    int aoff[4], boff[4];
    #pragma unroll
    for (int i = 0; i < 4; ++i) {
        aoff[i] = (wm * 64 + i * 16 + fr) * 32 + kg * 8;
        boff[i] = (wn * 64 + i * 16 + fr) * 32 + kg * 8;
    }

    f32x4 acc[4][4];
    #pragma unroll
    for (int i = 0; i < 4; ++i)
        #pragma unroll
        for (int j = 0; j < 4; ++j)
            acc[i][j] = (f32x4)0.f;

    for (int k0 = 0; k0 < Ksub; k0 += 32) {
        #pragma unroll
        for (int t = 0; t < 2; ++t) {
            __builtin_amdgcn_global_load_lds(
                (const __attribute__((address_space(1))) void*)(Ag + offA[t] + k0),
                (__attribute__((address_space(3))) void*)(&smA[(wave * 2 + t) * 512]),
                16, 0, 0);
            __builtin_amdgcn_global_load_lds(
                (const __attribute__((address_space(1))) void*)(Bg + offB[t] + k0),
                (__attribute__((address_space(3))) void*)(&smB[(wave * 2 + t) * 512]),
                16, 0, 0);
        }
        __syncthreads();

        f16x8 aF[4], bF[4];
        #pragma unroll
        for (int i = 0; i < 4; ++i) aF[i] = *(const f16x8*)&smA[aoff[i]];
        #pragma unroll
        for (int j = 0; j < 4; ++j) bF[j] = *(const f16x8*)&smB[boff[j]];
        #pragma unroll
        for (int i = 0; i < 4; ++i)
            #pragma unroll
            for (int j = 0; j < 4; ++j)
                acc[i][j] = __builtin_amdgcn_mfma_f32_16x16x32_f16(aF[i], bF[j], acc[i][j], 0, 0, 0);
        __syncthreads();
    }

    // epilogue: D mapping col=lane&15, row=(lane>>4)*4+reg
    float*    Cf = (float*)Cout + bz * sC + ks * sK;
    ushort_t* Ch = (ushort_t*)Cout + bz * sC + ks * sK;
    #pragma unroll
    for (int i = 0; i < 4; ++i) {
        #pragma unroll
        for (int r = 0; r < 4; ++r) {
            const int grow = m0 + wm * 64 + i * 16 + kg * 4 + r;
            const float bM = biasM ? biasM[grow] : 0.f;
            float s = 0.f, q = 0.f;
            #pragma unroll
            for (int j = 0; j < 4; ++j) {
                const int gcol = n0 + wn * 64 + j * 16 + fr;
                const float bN = biasN ? biasN[gcol] : 0.f;
                const float v = acc[i][j][r] + bN + bM;
                if (OUT_F16) Ch[(long)grow * ldc + gcol] = f2h(v);
                else         Cf[(long)grow * ldc + gcol] = v;
                if (STATS) { s += v; q += v * v; }
            }
            if (STATS) {
                // reduce across the 16 fr-lanes (same kg -> same row)
                #pragma unroll
                for (int m = 1; m < 16; m <<= 1) {
                    s += __shfl_xor(s, m, 64);
                    q += __shfl_xor(q, m, 64);
                }
                if (fr == 0) {
                    atomicAdd(&sums[grow], s);
                    atomicAdd(&sumsq[grow], q);
                }
            }
        }
    }
}

// ---------------- transpose + convert: x (B,C,N) f32 -> xT (B,N,C) fp16 ----------------
__global__ __launch_bounds__(256)
void transpose_cvt(const float* __restrict__ x, ushort_t* __restrict__ xT)
{
    __shared__ ushort_t t[64][65];
    const int b  = blockIdx.z;
    const int n0 = blockIdx.x * 64, c0 = blockIdx.y * 64;
    const float*  xp = x  + ((long)b * C_ + c0) * NSP_ + n0;
    ushort_t*     op = xT + ((long)b * NSP_ + n0) * C_ + c0;
    const int tr = threadIdx.x >> 6;   // 0..3
    const int tc = threadIdx.x & 63;
    #pragma unroll
    for (int i = 0; i < 16; ++i) {
        const int row = tr * 16 + i;            // C direction
        t[row][tc] = f2h(xp[(long)row * NSP_ + tc]);
    }
    __syncthreads();
    #pragma unroll
    for (int i = 0; i < 16; ++i) {
        const int row = tr * 16 + i;            // N direction
        op[(long)row * C_ + tc] = t[tc][row];
    }
}

// ---------------- f32 -> fp16 convert ----------------
struct U4 { ushort_t a, b, c, d; };
__global__ __launch_bounds__(256)
void cvt4(const float* __restrict__ in, ushort_t* __restrict__ out, int n4)
{
    const int i = blockIdx.x * 256 + threadIdx.x;
    if (i < n4) {
        const float4 v = ((const float4*)in)[i];
        U4 u{f2h(v.x), f2h(v.y), f2h(v.z), f2h(v.w)};
        ((U4*)out)[i] = u;
    }
}

__global__ __launch_bounds__(256)
void concat_bias(const float* __restrict__ a, const float* __restrict__ b, float* __restrict__ o)
{
    const int i = blockIdx.x * 256 + threadIdx.x;
    if (i < CI_)            o[i] = a[i];
    else if (i < 2 * CI_)   o[i] = b[i - CI_];
}

// ---------------- row softmax (2048), fp16 in, fp16 out, dense ----------------
__global__ __launch_bounds__(256)
void softmax2048(const ushort_t* __restrict__ fh, ushort_t* __restrict__ attn)
{
    const long rid = blockIdx.x;
    const int tid = threadIdx.x;
    const uint4 w = ((const uint4*)(fh + rid * NSP_))[tid];
    ushort_t h[8];
    __builtin_memcpy(h, &w, 16);
    float v[8];
    #pragma unroll
    for (int i = 0; i < 8; ++i) v[i] = h2f(h[i]);

    float mx = v[0];
    #pragma unroll
    for (int i = 1; i < 8; ++i) mx = fmaxf(mx, v[i]);

    __shared__ float red[256];
    red[tid] = mx;
    __syncthreads();
    for (int s = 128; s > 0; s >>= 1) {
        if (tid < s) red[tid] = fmaxf(red[tid], red[tid + s]);
        __syncthreads();
    }
    mx = red[0];
    __syncthreads();

    float sum = 0.f;
    #pragma unroll
    for (int i = 0; i < 8; ++i) { v[i] = __expf(v[i] - mx); sum += v[i]; }
    red[tid] = sum;
    __syncthreads();
    for (int s = 128; s > 0; s >>= 1) {
        if (tid < s) red[tid] += red[tid + s];
        __syncthreads();
    }
    const float inv = 1.f / red[0];
    #pragma unroll
    for (int i = 0; i < 8; ++i) h[i] = f2h(v[i] * inv);
    uint4 wo;
    __builtin_memcpy(&wo, h, 16);
    ((uint4*)(attn + rid * NSP_))[tid] = wo;
}

// ---------------- combine split-K partials -> fp16 ----------------
__global__ __launch_bounds__(256)
void combine2(const float* __restrict__ p0, const float* __restrict__ p1,
              ushort_t* __restrict__ out)
{
    const long i = (long)blockIdx.x * 256 + threadIdx.x;   // 8 elems per thread
    const float4 a0 = ((const float4*)p0)[2 * i];
    const float4 a1 = ((const float4*)p0)[2 * i + 1];
    const float4 b0 = ((const float4*)p1)[2 * i];
    const float4 b1 = ((const float4*)p1)[2 * i + 1];
    ushort_t h[8] = {
        f2h(a0.x + b0.x), f2h(a0.y + b0.y), f2h(a0.z + b0.z), f2h(a0.w + b0.w),
        f2h(a1.x + b1.x), f2h(a1.y + b1.y), f2h(a1.z + b1.z), f2h(a1.w + b1.w)};
    uint4 wo;
    __builtin_memcpy(&wo, h, 16);
    ((uint4*)out)[i] = wo;
}

// ---------------- BN finalize: sums -> scale/shift ----------------
__global__ __launch_bounds__(256)
void bn_finalize(const float* __restrict__ sums, const float* __restrict__ sumsq,
                 const float* __restrict__ gamma, const float* __restrict__ beta,
                 float* __restrict__ scale, float* __restrict__ shift)
{
    const int c = blockIdx.x * 256 + threadIdx.x;
    if (c < C_) {
        const float inv = 1.f / (float)(B_ * NSP_);
        const float mean = sums[c] * inv;
        const float var  = sumsq[c] * inv - mean * mean;
        const float sc = rsqrtf(var + EPS_) * gamma[c];
        scale[c] = sc;
        shift[c] = beta[c] - mean * sc;
    }
}

// ---------------- BN apply + residual: out = wy*scale[c] + shift[c] + x ----------------
__global__ __launch_bounds__(256)
void bn_apply(const ushort_t* __restrict__ wy, const float* __restrict__ x,
              const float* __restrict__ scale, const float* __restrict__ shift,
              float* __restrict__ out)
{
    const long total8 = (long)B_ * C_ * NSP_ / 8;   // 1,048,576
    for (long i = (long)blockIdx.x * 256 + threadIdx.x; i < total8;
         i += (long)gridDim.x * 256) {
        const int c = (int)((i >> 8) & (C_ - 1));   // NSP_/8 = 256 groups per channel
        const uint4 ww = ((const uint4*)wy)[i];
        ushort_t h[8];
        __builtin_memcpy(h, &ww, 16);
        const float4 x0 = ((const float4*)x)[2 * i];
        const float4 x1 = ((const float4*)x)[2 * i + 1];
        const float sc = scale[c], sh = shift[c];
        float4 o0, o1;
        o0.x = h2f(h[0]) * sc + sh + x0.x;
        o0.y = h2f(h[1]) * sc + sh + x0.y;
        o0.z = h2f(h[2]) * sc + sh + x0.z;
        o0.w = h2f(h[3]) * sc + sh + x0.w;
        o1.x = h2f(h[4]) * sc + sh + x1.x;
        o1.y = h2f(h[5]) * sc + sh + x1.y;
        o1.z = h2f(h[6]) * sc + sh + x1.z;
        o1.w = h2f(h[7]) * sc + sh + x1.w;
        ((float4*)out)[2 * i]     = o0;
        ((float4*)out)[2 * i + 1] = o1;
    }
}

extern "C" void kernel_launch(void* const* d_in, const int* in_sizes, int n_in,
                              void* d_out, int out_size, void* d_ws, size_t ws_size,
                              hipStream_t stream)
{
    const float* x     = (const float*)d_in[0];
    const float* g_w   = (const float*)d_in[1];
    const float* g_b   = (const float*)d_in[2];
    const float* th_w  = (const float*)d_in[3];
    const float* th_b  = (const float*)d_in[4];
    const float* ph_w  = (const float*)d_in[5];
    const float* ph_b  = (const float*)d_in[6];
    const float* w_w   = (const float*)d_in[7];
    const float* w_b   = (const float*)d_in[8];
    const float* gamma = (const float*)d_in[9];
    const float* beta  = (const float*)d_in[10];
    float* out = (float*)d_out;
    char*  ws  = (char*)d_ws;

    // ---- workspace carve (bytes), total ~111.2 MB (< proven 117.4 MB) ----
    ushort_t* xT      = (ushort_t*)(ws + 0);           // 16 MB  (B,N,C) fp16
    ushort_t* tw      = (ushort_t*)(ws + 16777216);    //  2 MB
    ushort_t* g_w_h   = (ushort_t*)(ws + 18874368);    //  1 MB
    ushort_t* w_w_h   = (ushort_t*)(ws + 19922944);    //  1 MB
    ushort_t* thph    = (ushort_t*)(ws + 20971520);    // 16 MB  (B,N,1024) [dead after f] -> y
    ushort_t* gcn     = (ushort_t*)(ws + 37748736);    //  8 MB  (B,CI,N)
    ushort_t* fh      = (ushort_t*)(ws + 46137344);    // 32 MB  (B,N,N) fp16 [dead after softmax] -> yp0/yp1
    ushort_t* attn    = (ushort_t*)(ws + 79691776);    // 32 MB  (B,N,N) fp16 [dead after y] -> wy
    float*    bias_tp = (float*)   (ws + 111149056);
    float*    sums    = (float*)   (ws + 111153152);
    float*    sumsq   = (float*)   (ws + 111157248);
    float*    scale   = (float*)   (ws + 111161344);
    float*    shift   = (float*)   (ws + 111165440);

    float*    yp   = (float*)fh;           // 2 x 16 MB fp32 partials (after softmax)
    ushort_t* y    = thph;                 // 8 MB fp16 (after f GEMM)
    ushort_t* wy   = attn;                 // 16 MB fp16 (after y GEMM)

    const dim3 blk(256);

    // 1) x -> xT fp16 (transpose)
    transpose_cvt<<<dim3(NSP_ / 64, C_ / 64, B_), blk, 0, stream>>>(x, xT);

    // 2) weight conversions + zero BN accumulators
    cvt4<<<512, blk, 0, stream>>>(th_w, tw,          131072);
    cvt4<<<512, blk, 0, stream>>>(ph_w, tw + 524288, 131072);
    cvt4<<<512, blk, 0, stream>>>(g_w,  g_w_h,       131072);
    cvt4<<<512, blk, 0, stream>>>(w_w,  w_w_h,       131072);
    concat_bias<<<4, blk, 0, stream>>>(th_b, ph_b, bias_tp);
    hipMemsetAsync(sums,  0, C_ * sizeof(float), stream);
    hipMemsetAsync(sumsq, 0, C_ * sizeof(float), stream);

    // 3) theta|phi : (B, N, 1024) = xT . tw^T + bias
    gemm_tn<true, 1, false><<<dim3(1024 / 128, NSP_ / 128, B_), blk, 0, stream>>>(
        xT, tw, thph, nullptr, bias_tp,
        1024, C_, C_, C_, 1024, (long)NSP_ * C_, 0, (long)NSP_ * 1024, 0,
        nullptr, nullptr);

    // 4) g : (B, CI, N) = g_w . xT^T + g_b
    gemm_tn<true, 1, false><<<dim3(NSP_ / 128, CI_ / 128, B_), blk, 0, stream>>>(
        g_w_h, xT, gcn, g_b, nullptr,
        NSP_, C_, C_, C_, NSP_, 0, (long)NSP_ * C_, (long)CI_ * NSP_, 0,
        nullptr, nullptr);

    // 5) f : (B, N, N) fp16 = theta . phi^T
    gemm_tn<true, 1, false><<<dim3(NSP_ / 128, NSP_ / 128, B_), blk, 0, stream>>>(
        thph, thph + CI_, fh, nullptr, nullptr,
        NSP_, CI_, 1024, 1024, NSP_,
        (long)NSP_ * 1024, (long)NSP_ * 1024, (long)NSP_ * NSP_, 0,
        nullptr, nullptr);

    // 6) softmax rows -> attn fp16 (dense)
    softmax2048<<<B_ * NSP_, blk, 0, stream>>>(fh, attn);

    // 7) y partials (split-K=2): (B, N, CI) fp32 x2 = attn . gcn^T
    gemm_tn<false, 2, false><<<dim3(CI_ / 128, NSP_ / 128, B_ * 2), blk, 0, stream>>>(
        attn, gcn, yp, nullptr, nullptr,
        CI_, NSP_, NSP_, NSP_, CI_,
        (long)NSP_ * NSP_, (long)CI_ * NSP_, (long)NSP_ * CI_,
        (long)B_ * NSP_ * CI_, nullptr, nullptr);

    // 7b) y = fp16(yp0 + yp1)
    combine2<<<8192, blk, 0, stream>>>(yp, yp + (long)B_ * NSP_ * CI_, y);

    // 8) w_y : (B, C, N) fp16 = w_w . y^T + w_b  (+ fused BN stats)
    gemm_tn<true, 1, true><<<dim3(NSP_ / 128, C_ / 128, B_), blk, 0, stream>>>(
        w_w_h, y, wy, w_b, nullptr,
        NSP_, CI_, CI_, CI_, NSP_, 0, (long)NSP_ * CI_, (long)C_ * NSP_, 0,
        sums, sumsq);

    // 9) BN finalize + apply + residual
    bn_finalize<<<4, blk, 0, stream>>>(sums, sumsq, gamma, beta, scale, shift);
    bn_apply<<<2048, blk, 0, stream>>>(wy, x, scale, shift, out);
}